// Round 6
// baseline (1022.059 us; speedup 1.0000x reference)
//
#include <hip/hip_runtime.h>
#include <hip/hip_fp16.h>
#include <math.h>

#define NN 500000
#define BSZ 512                      // nodes per bucket
#define NBK ((NN + BSZ - 1) / BSZ)   // 977 buckets
#define CHUNK 16384                  // edges per partition/hist block

typedef __attribute__((ext_vector_type(4))) _Float16 half4;
typedef __attribute__((ext_vector_type(2))) _Float16 half2v;
typedef __attribute__((ext_vector_type(4))) int int4v;   // clang vector: ok for nontemporal builtins

// ---------- pass 1: bucket histogram (LDS-staged) + per-block counts -------
__global__ void hist_kernel(const int* __restrict__ col, int* __restrict__ bucketCount,
                            int* __restrict__ blkCnt, int E) {
    __shared__ int cnt[1024];
    int t = threadIdx.x;
    for (int i = t; i < 1024; i += 256) cnt[i] = 0;
    __syncthreads();
    int base = blockIdx.x * CHUNK;
    int end = base + CHUNK; if (end > E) end = E;
    int j = base + t * 4;
    for (; j + 3 < end; j += 1024) {
        int4v c = __builtin_nontemporal_load(reinterpret_cast<const int4v*>(col + j));
        atomicAdd(&cnt[c.x >> 9], 1);
        atomicAdd(&cnt[c.y >> 9], 1);
        atomicAdd(&cnt[c.z >> 9], 1);
        atomicAdd(&cnt[c.w >> 9], 1);
    }
    if (j < end) for (int k = j; k < end; ++k) atomicAdd(&cnt[col[k] >> 9], 1);
    __syncthreads();
    int* myCnt = blkCnt + (size_t)blockIdx.x * 1024;
    for (int b = t; b < 1024; b += 256) {
        int c = cnt[b];
        myCnt[b] = c;
        if (c) atomicAdd(&bucketCount[b], c);
    }
}

// ---------- pass 2: exclusive scan of 1024 bucket counts (1 block) ---------
__global__ void scan_kernel(const int* __restrict__ bucketCount, int* __restrict__ bucketStart,
                            int* __restrict__ gcursor) {
    __shared__ int ls[1024];
    int t = threadIdx.x;
    int v = bucketCount[t];
    ls[t] = v;
    __syncthreads();
    for (int off = 1; off < 1024; off <<= 1) {
        int u = (t >= off) ? ls[t - off] : 0;
        __syncthreads();
        ls[t] += u;
        __syncthreads();
    }
    int excl = ls[t] - v;
    bucketStart[t] = excl;
    gcursor[t] = excl;
}

// ---------- pass 3: partition edges into buckets (chunk reservation) -------
__global__ void part_kernel(const int* __restrict__ row, const int* __restrict__ col,
                            int* __restrict__ gcursor, const int* __restrict__ blkCnt,
                            int* __restrict__ recs, int E) {
    __shared__ int cnt[1024];
    __shared__ int basex[1024];
    int t = threadIdx.x;
    // phase B: reserve contiguous space per bucket using hist's per-block counts
    const int* myCnt = blkCnt + (size_t)blockIdx.x * 1024;
    for (int b = t; b < 1024; b += 256) {
        int c = myCnt[b];
        basex[b] = c ? atomicAdd(&gcursor[b], c) : 0;
        cnt[b] = 0;
    }
    __syncthreads();
    int base = blockIdx.x * CHUNK;
    int end = base + CHUNK; if (end > E) end = E;
    // phase C: write packed records at reserved ranks
    int j = base + t * 4;
    for (; j + 3 < end; j += 1024) {
        int4v r = __builtin_nontemporal_load(reinterpret_cast<const int4v*>(row + j));
        int4v c = __builtin_nontemporal_load(reinterpret_cast<const int4v*>(col + j));
        int b, rk;
        b = c.x >> 9; rk = atomicAdd(&cnt[b], 1); recs[basex[b] + rk] = (r.x << 9) | (c.x & 511);
        b = c.y >> 9; rk = atomicAdd(&cnt[b], 1); recs[basex[b] + rk] = (r.y << 9) | (c.y & 511);
        b = c.z >> 9; rk = atomicAdd(&cnt[b], 1); recs[basex[b] + rk] = (r.z << 9) | (c.z & 511);
        b = c.w >> 9; rk = atomicAdd(&cnt[b], 1); recs[basex[b] + rk] = (r.w << 9) | (c.w & 511);
    }
    if (j < end) {
        for (int k = j; k < end; ++k) {
            int b = col[k] >> 9;
            int rk = atomicAdd(&cnt[b], 1);
            recs[basex[b] + rk] = (row[k] << 9) | (col[k] & 511);
        }
    }
}

// ---------- pass 4: per-bucket degree count -> dinv (no global atomics) ----
__global__ void deg_kernel(const int* __restrict__ bucketStart, const int* __restrict__ bucketCount,
                           const int* __restrict__ recs, float* __restrict__ dinv, int N) {
    __shared__ int cnt[BSZ];
    int t = threadIdx.x, b = blockIdx.x;
    for (int i = t; i < BSZ; i += 256) cnt[i] = 0;
    __syncthreads();
    int s = bucketStart[b], e = s + bucketCount[b];
    for (int j = s + t; j < e; j += 256) {
        int u = __builtin_nontemporal_load(recs + j);
        atomicAdd(&cnt[u & 511], 1);
    }
    __syncthreads();
    int nodeBase = b * BSZ;
    for (int n = t; n < BSZ; n += 256) {
        int i = nodeBase + n;
        if (i < N) dinv[i] = rsqrtf((float)cnt[n] + 1.0f);
    }
}

// ---------- prep: g1 = fp16( dinv * (x @ W1) ) -----------------------------
__global__ void prep_kernel(const float* __restrict__ x, const float* __restrict__ W1,
                            const float* __restrict__ dinv, half4* __restrict__ g1h, int N) {
    int i = blockIdx.x * blockDim.x + threadIdx.x;
    if (i >= N) return;
    float d = dinv[i];
    float acc0 = 0.f, acc1 = 0.f, acc2 = 0.f, acc3 = 0.f;
#pragma unroll
    for (int k = 0; k < 9; ++k) {
        float xv = x[i * 9 + k];
        acc0 += xv * W1[k * 4 + 0];
        acc1 += xv * W1[k * 4 + 1];
        acc2 += xv * W1[k * 4 + 2];
        acc3 += xv * W1[k * 4 + 3];
    }
    half4 h;
    h.x = (_Float16)(d * acc0);
    h.y = (_Float16)(d * acc1);
    h.z = (_Float16)(d * acc2);
    h.w = (_Float16)(d * acc3);
    g1h[i] = h;
}

// ---------- agg layer 1 (LDS accumulate, native ds_add_f32) + mid fused ----
__global__ void agg1_kernel(const int* __restrict__ bucketStart, const int* __restrict__ bucketCount,
                            const int* __restrict__ recs, const float* __restrict__ dinv,
                            const half4* __restrict__ g1h, const float* __restrict__ b1,
                            const float* __restrict__ W2, half2v* __restrict__ g2h, int N) {
    __shared__ float acc[4][BSZ + 8];
    int t = threadIdx.x, b = blockIdx.x;
    for (int i = t; i < BSZ; i += 256) {
        acc[0][i] = 0.f; acc[1][i] = 0.f; acc[2][i] = 0.f; acc[3][i] = 0.f;
    }
    __syncthreads();
    int s = bucketStart[b], e = s + bucketCount[b];
    for (int j = s + t; j < e; j += 256) {
        unsigned u = (unsigned)__builtin_nontemporal_load(recs + j);
        int r = u >> 9, cl = u & 511;
        half4 g = g1h[r];
        unsafeAtomicAdd(&acc[0][cl], (float)g.x);   // native ds_add_f32, no CAS loop
        unsafeAtomicAdd(&acc[1][cl], (float)g.y);
        unsafeAtomicAdd(&acc[2][cl], (float)g.z);
        unsafeAtomicAdd(&acc[3][cl], (float)g.w);
    }
    __syncthreads();
    int nodeBase = b * BSZ;
    for (int n = t; n < BSZ; n += 256) {
        int i = nodeBase + n;
        if (i >= N) continue;
        half4 self = g1h[i];
        float di = dinv[i];
        float t0 = tanhf(di * (acc[0][n] + (float)self.x) + b1[0]);
        float t1 = tanhf(di * (acc[1][n] + (float)self.y) + b1[1]);
        float t2 = tanhf(di * (acc[2][n] + (float)self.z) + b1[2]);
        float t3 = tanhf(di * (acc[3][n] + (float)self.w) + b1[3]);
        float o0 = t0 * W2[0] + t1 * W2[2] + t2 * W2[4] + t3 * W2[6];
        float o1 = t0 * W2[1] + t1 * W2[3] + t2 * W2[5] + t3 * W2[7];
        half2v g2;
        g2.x = (_Float16)(di * o0);
        g2.y = (_Float16)(di * o1);
        g2h[i] = g2;
    }
}

// ---------- agg layer 2 (LDS accumulate, native ds_add_f32) + final fused --
__global__ void agg2_kernel(const int* __restrict__ bucketStart, const int* __restrict__ bucketCount,
                            const int* __restrict__ recs, const float* __restrict__ dinv,
                            const half2v* __restrict__ g2h, const float* __restrict__ b2,
                            float* __restrict__ out, int N) {
    __shared__ float acc[2][BSZ + 8];
    int t = threadIdx.x, b = blockIdx.x;
    for (int i = t; i < BSZ; i += 256) { acc[0][i] = 0.f; acc[1][i] = 0.f; }
    __syncthreads();
    int s = bucketStart[b], e = s + bucketCount[b];
    for (int j = s + t; j < e; j += 256) {
        unsigned u = (unsigned)__builtin_nontemporal_load(recs + j);
        int r = u >> 9, cl = u & 511;
        half2v g = g2h[r];
        unsafeAtomicAdd(&acc[0][cl], (float)g.x);
        unsafeAtomicAdd(&acc[1][cl], (float)g.y);
    }
    __syncthreads();
    int nodeBase = b * BSZ;
    for (int n = t; n < BSZ; n += 256) {
        int i = nodeBase + n;
        if (i >= N) continue;
        half2v self = g2h[i];
        float di = dinv[i];
        reinterpret_cast<float2*>(out)[i] =
            make_float2(di * (acc[0][n] + (float)self.x) + b2[0],
                        di * (acc[1][n] + (float)self.y) + b2[1]);
    }
}

extern "C" void kernel_launch(void* const* d_in, const int* in_sizes, int n_in,
                              void* d_out, int out_size, void* d_ws, size_t ws_size,
                              hipStream_t stream) {
    const float* x  = (const float*)d_in[0];
    const int*   ei = (const int*)d_in[1];   // [2, E] int32
    const float* W1 = (const float*)d_in[2];
    const float* b1 = (const float*)d_in[3];
    const float* W2 = (const float*)d_in[4];
    const float* b2 = (const float*)d_in[5];
    float* out = (float*)d_out;

    const int N = NN;
    const int E = in_sizes[1] / 2;           // 16,000,000
    const int* row = ei;                     // edge_index[0] = source
    const int* col = ei + E;                 // edge_index[1] = target

    const int nchunks = (E + CHUNK - 1) / CHUNK;          // 977

    // ws layout (16B aligned):
    // bucketCount @0 (4K), bucketStart @4K, gcursor @8K,
    // blkCnt @16K (nchunks*4KB ~ 3.82MB), dinv @16K+4M (2MB),
    // g1h @16K+6M (4MB), g2h @16K+10M (2MB), recs @16K+12M (64MB)  => ~76MB
    char* ws = (char*)d_ws;
    int*    bucketCount = (int*)ws;
    int*    bucketStart = (int*)(ws + 4096);
    int*    gcursor     = (int*)(ws + 8192);
    int*    blkCnt      = (int*)(ws + 16384);
    float*  dinv        = (float*)(ws + 16384 + 4194304ull);
    half4*  g1h         = (half4*)(ws + 16384 + 6291456ull);
    half2v* g2h         = (half2v*)(ws + 16384 + 10485760ull);
    int*    recs        = (int*)(ws + 16384 + 12582912ull);

    (void)hipMemsetAsync(bucketCount, 0, 4096, stream);

    const int ngrid = (N + 255) / 256;                    // 1954

    hist_kernel<<<nchunks, 256, 0, stream>>>(col, bucketCount, blkCnt, E);
    scan_kernel<<<1, 1024, 0, stream>>>(bucketCount, bucketStart, gcursor);
    part_kernel<<<nchunks, 256, 0, stream>>>(row, col, gcursor, blkCnt, recs, E);
    deg_kernel <<<NBK, 256, 0, stream>>>(bucketStart, bucketCount, recs, dinv, N);
    prep_kernel<<<ngrid, 256, 0, stream>>>(x, W1, dinv, g1h, N);
    agg1_kernel<<<NBK, 256, 0, stream>>>(bucketStart, bucketCount, recs, dinv, g1h, b1, W2, g2h, N);
    agg2_kernel<<<NBK, 256, 0, stream>>>(bucketStart, bucketCount, recs, dinv, g2h, b2, out, N);
}

// Round 7
// 1013.951 us; speedup vs baseline: 1.0080x; 1.0080x over previous
//
#include <hip/hip_runtime.h>
#include <hip/hip_fp16.h>
#include <math.h>

#define NN 500000
#define BSZ 512                      // nodes per bucket
#define NBK ((NN + BSZ - 1) / BSZ)   // 977 buckets
#define CHUNK 16384                  // edges per partition/hist block
#define ATB 1024                     // threads per agg block

typedef __attribute__((ext_vector_type(4))) _Float16 half4;
typedef __attribute__((ext_vector_type(2))) _Float16 half2v;
typedef __attribute__((ext_vector_type(4))) int int4v;

// ---------- pass 1: bucket histogram (LDS-staged) + per-block counts -------
__global__ void hist_kernel(const int* __restrict__ col, int* __restrict__ bucketCount,
                            int* __restrict__ blkCnt, int E) {
    __shared__ int cnt[1024];
    int t = threadIdx.x;
    for (int i = t; i < 1024; i += 256) cnt[i] = 0;
    __syncthreads();
    int base = blockIdx.x * CHUNK;
    int end = base + CHUNK; if (end > E) end = E;
    int j = base + t * 4;
    for (; j + 3 < end; j += 1024) {
        int4v c = __builtin_nontemporal_load(reinterpret_cast<const int4v*>(col + j));
        atomicAdd(&cnt[c.x >> 9], 1);
        atomicAdd(&cnt[c.y >> 9], 1);
        atomicAdd(&cnt[c.z >> 9], 1);
        atomicAdd(&cnt[c.w >> 9], 1);
    }
    if (j < end) for (int k = j; k < end; ++k) atomicAdd(&cnt[col[k] >> 9], 1);
    __syncthreads();
    int* myCnt = blkCnt + (size_t)blockIdx.x * 1024;
    for (int b = t; b < 1024; b += 256) {
        int c = cnt[b];
        myCnt[b] = c;
        if (c) atomicAdd(&bucketCount[b], c);
    }
}

// ---------- pass 2: exclusive scan of 1024 bucket counts (1 block) ---------
__global__ void scan_kernel(const int* __restrict__ bucketCount, int* __restrict__ bucketStart,
                            int* __restrict__ gcursor) {
    __shared__ int ls[1024];
    int t = threadIdx.x;
    int v = bucketCount[t];
    ls[t] = v;
    __syncthreads();
    for (int off = 1; off < 1024; off <<= 1) {
        int u = (t >= off) ? ls[t - off] : 0;
        __syncthreads();
        ls[t] += u;
        __syncthreads();
    }
    int excl = ls[t] - v;
    bucketStart[t] = excl;
    gcursor[t] = excl;
}

// ---------- pass 3: partition edges into buckets (chunk reservation) -------
__global__ void part_kernel(const int* __restrict__ row, const int* __restrict__ col,
                            int* __restrict__ gcursor, const int* __restrict__ blkCnt,
                            int* __restrict__ recs, int E) {
    __shared__ int cnt[1024];
    __shared__ int basex[1024];
    int t = threadIdx.x;
    const int* myCnt = blkCnt + (size_t)blockIdx.x * 1024;
    for (int b = t; b < 1024; b += 256) {
        int c = myCnt[b];
        basex[b] = c ? atomicAdd(&gcursor[b], c) : 0;
        cnt[b] = 0;
    }
    __syncthreads();
    int base = blockIdx.x * CHUNK;
    int end = base + CHUNK; if (end > E) end = E;
    int j = base + t * 4;
    for (; j + 3 < end; j += 1024) {
        int4v r = __builtin_nontemporal_load(reinterpret_cast<const int4v*>(row + j));
        int4v c = __builtin_nontemporal_load(reinterpret_cast<const int4v*>(col + j));
        int b, rk;
        b = c.x >> 9; rk = atomicAdd(&cnt[b], 1); recs[basex[b] + rk] = (r.x << 9) | (c.x & 511);
        b = c.y >> 9; rk = atomicAdd(&cnt[b], 1); recs[basex[b] + rk] = (r.y << 9) | (c.y & 511);
        b = c.z >> 9; rk = atomicAdd(&cnt[b], 1); recs[basex[b] + rk] = (r.z << 9) | (c.z & 511);
        b = c.w >> 9; rk = atomicAdd(&cnt[b], 1); recs[basex[b] + rk] = (r.w << 9) | (c.w & 511);
    }
    if (j < end) {
        for (int k = j; k < end; ++k) {
            int b = col[k] >> 9;
            int rk = atomicAdd(&cnt[b], 1);
            recs[basex[b] + rk] = (row[k] << 9) | (col[k] & 511);
        }
    }
}

// ---------- pass 4: per-bucket degree count -> dinv (1024 thr, 4-way MLP) --
__global__ void deg_kernel(const int* __restrict__ bucketStart, const int* __restrict__ bucketCount,
                           const int* __restrict__ recs, float* __restrict__ dinv, int N) {
    __shared__ int cnt[BSZ];
    int t = threadIdx.x, b = blockIdx.x;
    for (int i = t; i < BSZ; i += ATB) cnt[i] = 0;
    __syncthreads();
    int s = bucketStart[b], e = s + bucketCount[b];
    int nIter = (e - s) / (ATB * 4);
    int mainEnd = s + nIter * (ATB * 4);
    for (int base = s; base < mainEnd; base += ATB * 4) {
        int idx = base + t * 4;
        int u0 = recs[idx], u1 = recs[idx + 1], u2 = recs[idx + 2], u3 = recs[idx + 3];
        atomicAdd(&cnt[u0 & 511], 1);
        atomicAdd(&cnt[u1 & 511], 1);
        atomicAdd(&cnt[u2 & 511], 1);
        atomicAdd(&cnt[u3 & 511], 1);
    }
    for (int j = mainEnd + t; j < e; j += ATB) atomicAdd(&cnt[recs[j] & 511], 1);
    __syncthreads();
    int nodeBase = b * BSZ;
    for (int n = t; n < BSZ; n += ATB) {
        int i = nodeBase + n;
        if (i < N) dinv[i] = rsqrtf((float)cnt[n] + 1.0f);
    }
}

// ---------- prep: g1 = fp16( dinv * (x @ W1) ) -----------------------------
__global__ void prep_kernel(const float* __restrict__ x, const float* __restrict__ W1,
                            const float* __restrict__ dinv, half4* __restrict__ g1h, int N) {
    int i = blockIdx.x * blockDim.x + threadIdx.x;
    if (i >= N) return;
    float d = dinv[i];
    float acc0 = 0.f, acc1 = 0.f, acc2 = 0.f, acc3 = 0.f;
#pragma unroll
    for (int k = 0; k < 9; ++k) {
        float xv = x[i * 9 + k];
        acc0 += xv * W1[k * 4 + 0];
        acc1 += xv * W1[k * 4 + 1];
        acc2 += xv * W1[k * 4 + 2];
        acc3 += xv * W1[k * 4 + 3];
    }
    half4 h;
    h.x = (_Float16)(d * acc0);
    h.y = (_Float16)(d * acc1);
    h.z = (_Float16)(d * acc2);
    h.w = (_Float16)(d * acc3);
    g1h[i] = h;
}

// ---------- agg layer 1: 1024 threads, 4 gathers in flight -----------------
__global__ void agg1_kernel(const int* __restrict__ bucketStart, const int* __restrict__ bucketCount,
                            const int* __restrict__ recs, const float* __restrict__ dinv,
                            const half4* __restrict__ g1h, const float* __restrict__ b1,
                            const float* __restrict__ W2, half2v* __restrict__ g2h, int N) {
    __shared__ float acc[4][BSZ + 8];
    int t = threadIdx.x, b = blockIdx.x;
    for (int i = t; i < BSZ; i += ATB) {
        acc[0][i] = 0.f; acc[1][i] = 0.f; acc[2][i] = 0.f; acc[3][i] = 0.f;
    }
    __syncthreads();
    int s = bucketStart[b], e = s + bucketCount[b];
    int nIter = (e - s) / (ATB * 4);
    int mainEnd = s + nIter * (ATB * 4);
    for (int base = s; base < mainEnd; base += ATB * 4) {
        int idx = base + t * 4;
        unsigned u0 = (unsigned)recs[idx];
        unsigned u1 = (unsigned)recs[idx + 1];
        unsigned u2 = (unsigned)recs[idx + 2];
        unsigned u3 = (unsigned)recs[idx + 3];
        half4 ga = g1h[u0 >> 9];     // 4 independent random loads in flight
        half4 gb = g1h[u1 >> 9];
        half4 gc = g1h[u2 >> 9];
        half4 gd = g1h[u3 >> 9];
        int c0 = u0 & 511, c1 = u1 & 511, c2 = u2 & 511, c3 = u3 & 511;
        unsafeAtomicAdd(&acc[0][c0], (float)ga.x);
        unsafeAtomicAdd(&acc[1][c0], (float)ga.y);
        unsafeAtomicAdd(&acc[2][c0], (float)ga.z);
        unsafeAtomicAdd(&acc[3][c0], (float)ga.w);
        unsafeAtomicAdd(&acc[0][c1], (float)gb.x);
        unsafeAtomicAdd(&acc[1][c1], (float)gb.y);
        unsafeAtomicAdd(&acc[2][c1], (float)gb.z);
        unsafeAtomicAdd(&acc[3][c1], (float)gb.w);
        unsafeAtomicAdd(&acc[0][c2], (float)gc.x);
        unsafeAtomicAdd(&acc[1][c2], (float)gc.y);
        unsafeAtomicAdd(&acc[2][c2], (float)gc.z);
        unsafeAtomicAdd(&acc[3][c2], (float)gc.w);
        unsafeAtomicAdd(&acc[0][c3], (float)gd.x);
        unsafeAtomicAdd(&acc[1][c3], (float)gd.y);
        unsafeAtomicAdd(&acc[2][c3], (float)gd.z);
        unsafeAtomicAdd(&acc[3][c3], (float)gd.w);
    }
    for (int j = mainEnd + t; j < e; j += ATB) {
        unsigned u = (unsigned)recs[j];
        int r = u >> 9, cl = u & 511;
        half4 g = g1h[r];
        unsafeAtomicAdd(&acc[0][cl], (float)g.x);
        unsafeAtomicAdd(&acc[1][cl], (float)g.y);
        unsafeAtomicAdd(&acc[2][cl], (float)g.z);
        unsafeAtomicAdd(&acc[3][cl], (float)g.w);
    }
    __syncthreads();
    int nodeBase = b * BSZ;
    for (int n = t; n < BSZ; n += ATB) {
        int i = nodeBase + n;
        if (i >= N) continue;
        half4 self = g1h[i];
        float di = dinv[i];
        float t0 = tanhf(di * (acc[0][n] + (float)self.x) + b1[0]);
        float t1 = tanhf(di * (acc[1][n] + (float)self.y) + b1[1]);
        float t2 = tanhf(di * (acc[2][n] + (float)self.z) + b1[2]);
        float t3 = tanhf(di * (acc[3][n] + (float)self.w) + b1[3]);
        float o0 = t0 * W2[0] + t1 * W2[2] + t2 * W2[4] + t3 * W2[6];
        float o1 = t0 * W2[1] + t1 * W2[3] + t2 * W2[5] + t3 * W2[7];
        half2v g2;
        g2.x = (_Float16)(di * o0);
        g2.y = (_Float16)(di * o1);
        g2h[i] = g2;
    }
}

// ---------- agg layer 2: 1024 threads, 4 gathers in flight -----------------
__global__ void agg2_kernel(const int* __restrict__ bucketStart, const int* __restrict__ bucketCount,
                            const int* __restrict__ recs, const float* __restrict__ dinv,
                            const half2v* __restrict__ g2h, const float* __restrict__ b2,
                            float* __restrict__ out, int N) {
    __shared__ float acc[2][BSZ + 8];
    int t = threadIdx.x, b = blockIdx.x;
    for (int i = t; i < BSZ; i += ATB) { acc[0][i] = 0.f; acc[1][i] = 0.f; }
    __syncthreads();
    int s = bucketStart[b], e = s + bucketCount[b];
    int nIter = (e - s) / (ATB * 4);
    int mainEnd = s + nIter * (ATB * 4);
    for (int base = s; base < mainEnd; base += ATB * 4) {
        int idx = base + t * 4;
        unsigned u0 = (unsigned)recs[idx];
        unsigned u1 = (unsigned)recs[idx + 1];
        unsigned u2 = (unsigned)recs[idx + 2];
        unsigned u3 = (unsigned)recs[idx + 3];
        half2v ga = g2h[u0 >> 9];
        half2v gb = g2h[u1 >> 9];
        half2v gc = g2h[u2 >> 9];
        half2v gd = g2h[u3 >> 9];
        int c0 = u0 & 511, c1 = u1 & 511, c2 = u2 & 511, c3 = u3 & 511;
        unsafeAtomicAdd(&acc[0][c0], (float)ga.x);
        unsafeAtomicAdd(&acc[1][c0], (float)ga.y);
        unsafeAtomicAdd(&acc[0][c1], (float)gb.x);
        unsafeAtomicAdd(&acc[1][c1], (float)gb.y);
        unsafeAtomicAdd(&acc[0][c2], (float)gc.x);
        unsafeAtomicAdd(&acc[1][c2], (float)gc.y);
        unsafeAtomicAdd(&acc[0][c3], (float)gd.x);
        unsafeAtomicAdd(&acc[1][c3], (float)gd.y);
    }
    for (int j = mainEnd + t; j < e; j += ATB) {
        unsigned u = (unsigned)recs[j];
        int r = u >> 9, cl = u & 511;
        half2v g = g2h[r];
        unsafeAtomicAdd(&acc[0][cl], (float)g.x);
        unsafeAtomicAdd(&acc[1][cl], (float)g.y);
    }
    __syncthreads();
    int nodeBase = b * BSZ;
    for (int n = t; n < BSZ; n += ATB) {
        int i = nodeBase + n;
        if (i >= N) continue;
        half2v self = g2h[i];
        float di = dinv[i];
        reinterpret_cast<float2*>(out)[i] =
            make_float2(di * (acc[0][n] + (float)self.x) + b2[0],
                        di * (acc[1][n] + (float)self.y) + b2[1]);
    }
}

extern "C" void kernel_launch(void* const* d_in, const int* in_sizes, int n_in,
                              void* d_out, int out_size, void* d_ws, size_t ws_size,
                              hipStream_t stream) {
    const float* x  = (const float*)d_in[0];
    const int*   ei = (const int*)d_in[1];   // [2, E] int32
    const float* W1 = (const float*)d_in[2];
    const float* b1 = (const float*)d_in[3];
    const float* W2 = (const float*)d_in[4];
    const float* b2 = (const float*)d_in[5];
    float* out = (float*)d_out;

    const int N = NN;
    const int E = in_sizes[1] / 2;           // 16,000,000
    const int* row = ei;
    const int* col = ei + E;

    const int nchunks = (E + CHUNK - 1) / CHUNK;          // 977

    char* ws = (char*)d_ws;
    int*    bucketCount = (int*)ws;
    int*    bucketStart = (int*)(ws + 4096);
    int*    gcursor     = (int*)(ws + 8192);
    int*    blkCnt      = (int*)(ws + 16384);
    float*  dinv        = (float*)(ws + 16384 + 4194304ull);
    half4*  g1h         = (half4*)(ws + 16384 + 6291456ull);
    half2v* g2h         = (half2v*)(ws + 16384 + 10485760ull);
    int*    recs        = (int*)(ws + 16384 + 12582912ull);

    (void)hipMemsetAsync(bucketCount, 0, 4096, stream);

    const int ngrid = (N + 255) / 256;

    hist_kernel<<<nchunks, 256, 0, stream>>>(col, bucketCount, blkCnt, E);
    scan_kernel<<<1, 1024, 0, stream>>>(bucketCount, bucketStart, gcursor);
    part_kernel<<<nchunks, 256, 0, stream>>>(row, col, gcursor, blkCnt, recs, E);
    deg_kernel <<<NBK, ATB, 0, stream>>>(bucketStart, bucketCount, recs, dinv, N);
    prep_kernel<<<ngrid, 256, 0, stream>>>(x, W1, dinv, g1h, N);
    agg1_kernel<<<NBK, ATB, 0, stream>>>(bucketStart, bucketCount, recs, dinv, g1h, b1, W2, g2h, N);
    agg2_kernel<<<NBK, ATB, 0, stream>>>(bucketStart, bucketCount, recs, dinv, g2h, b2, out, N);
}

// Round 8
// 883.411 us; speedup vs baseline: 1.1569x; 1.1478x over previous
//
#include <hip/hip_runtime.h>
#include <hip/hip_fp16.h>
#include <math.h>

#define NN 500000
#define BSZ 512                      // nodes per bucket
#define NBK ((NN + BSZ - 1) / BSZ)   // 977 buckets
#define CHUNK 16384                  // edges per partition/hist block
#define KMAX 20                      // max recs/thread in sort (20*1024=20480 >> max bucket ~17.1K)

typedef __attribute__((ext_vector_type(4))) _Float16 half4;
typedef __attribute__((ext_vector_type(2))) _Float16 half2v;
typedef __attribute__((ext_vector_type(4))) int int4v;

// ---------- pass 1: bucket histogram (LDS-staged) + per-block counts -------
__global__ void hist_kernel(const int* __restrict__ col, int* __restrict__ bucketCount,
                            unsigned short* __restrict__ blkCnt, int E) {
    __shared__ int cnt[1024];
    int t = threadIdx.x;
    for (int i = t; i < 1024; i += 256) cnt[i] = 0;
    __syncthreads();
    int base = blockIdx.x * CHUNK;
    int end = base + CHUNK; if (end > E) end = E;
    int j = base + t * 4;
    for (; j + 3 < end; j += 1024) {
        int4v c = __builtin_nontemporal_load(reinterpret_cast<const int4v*>(col + j));
        atomicAdd(&cnt[c.x >> 9], 1);
        atomicAdd(&cnt[c.y >> 9], 1);
        atomicAdd(&cnt[c.z >> 9], 1);
        atomicAdd(&cnt[c.w >> 9], 1);
    }
    if (j < end) for (int k = j; k < end; ++k) atomicAdd(&cnt[col[k] >> 9], 1);
    __syncthreads();
    unsigned short* myCnt = blkCnt + (size_t)blockIdx.x * 1024;
    for (int b = t; b < 1024; b += 256) {
        int c = cnt[b];
        myCnt[b] = (unsigned short)c;        // c <= CHUNK = 16384, fits
        if (c) atomicAdd(&bucketCount[b], c);
    }
}

// ---------- pass 2: exclusive scan of 1024 bucket counts (1 block) ---------
__global__ void scan_kernel(const int* __restrict__ bucketCount, int* __restrict__ bucketStart,
                            int* __restrict__ gcursor) {
    __shared__ int ls[1024];
    int t = threadIdx.x;
    int v = bucketCount[t];
    ls[t] = v;
    __syncthreads();
    for (int off = 1; off < 1024; off <<= 1) {
        int u = (t >= off) ? ls[t - off] : 0;
        __syncthreads();
        ls[t] += u;
        __syncthreads();
    }
    int excl = ls[t] - v;
    bucketStart[t] = excl;
    gcursor[t] = excl;
}

// ---------- pass 3: partition edges into buckets (chunk reservation) -------
__global__ void part_kernel(const int* __restrict__ row, const int* __restrict__ col,
                            int* __restrict__ gcursor, const unsigned short* __restrict__ blkCnt,
                            int* __restrict__ recs, int E) {
    __shared__ int cnt[1024];
    __shared__ int basex[1024];
    int t = threadIdx.x;
    const unsigned short* myCnt = blkCnt + (size_t)blockIdx.x * 1024;
    for (int b = t; b < 1024; b += 256) {
        int c = myCnt[b];
        basex[b] = c ? atomicAdd(&gcursor[b], c) : 0;
        cnt[b] = 0;
    }
    __syncthreads();
    int base = blockIdx.x * CHUNK;
    int end = base + CHUNK; if (end > E) end = E;
    int j = base + t * 4;
    for (; j + 3 < end; j += 1024) {
        int4v r = __builtin_nontemporal_load(reinterpret_cast<const int4v*>(row + j));
        int4v c = __builtin_nontemporal_load(reinterpret_cast<const int4v*>(col + j));
        int b, rk;
        b = c.x >> 9; rk = atomicAdd(&cnt[b], 1); recs[basex[b] + rk] = (r.x << 9) | (c.x & 511);
        b = c.y >> 9; rk = atomicAdd(&cnt[b], 1); recs[basex[b] + rk] = (r.y << 9) | (c.y & 511);
        b = c.z >> 9; rk = atomicAdd(&cnt[b], 1); recs[basex[b] + rk] = (r.z << 9) | (c.z & 511);
        b = c.w >> 9; rk = atomicAdd(&cnt[b], 1); recs[basex[b] + rk] = (r.w << 9) | (c.w & 511);
    }
    if (j < end) {
        for (int k = j; k < end; ++k) {
            int b = col[k] >> 9;
            int rk = atomicAdd(&cnt[b], 1);
            recs[basex[b] + rk] = (row[k] << 9) | (col[k] & 511);
        }
    }
}

// ---------- pass 4: per-bucket counting sort (register-buffered) -----------
// Rewrites recs segment in node-sorted order (storing plain row ids),
// emits nodeStart[] (absolute CSR offsets) and dinv[]. LDS atomics only for
// 512 counters; records ride in registers between read and scatter.
__global__ __launch_bounds__(1024) void sort_kernel(const int* __restrict__ bucketStart,
                                                    const int* __restrict__ bucketCount,
                                                    int* __restrict__ recs,
                                                    float* __restrict__ dinv,
                                                    int* __restrict__ nodeStart, int N, int E) {
    __shared__ int cnt[BSZ];
    __shared__ int sc[BSZ];
    int t = threadIdx.x, b = blockIdx.x;
    int s = bucketStart[b], m = bucketCount[b];
    int v[KMAX];
#pragma unroll
    for (int k = 0; k < KMAX; ++k) {
        int idx = t + k * 1024;
        v[k] = (idx < m) ? recs[s + idx] : -1;   // packed (r<<9)|cl, always >= 0
    }
    if (t < BSZ) cnt[t] = 0;
    __syncthreads();
    // count (consumes v[k] -> all loads complete before any barrier below)
#pragma unroll
    for (int k = 0; k < KMAX; ++k)
        if (v[k] >= 0) atomicAdd(&cnt[v[k] & 511], 1);
    __syncthreads();
    // inclusive scan over 512 counts
    if (t < BSZ) sc[t] = cnt[t];
    __syncthreads();
    for (int off = 1; off < BSZ; off <<= 1) {
        int u = 0;
        if (t < BSZ && t >= off) u = sc[t - off];
        __syncthreads();
        if (t < BSZ) sc[t] += u;
        __syncthreads();
    }
    if (t < BSZ) {
        int excl = sc[t] - cnt[t];
        int node = b * BSZ + t;
        if (node < N) {
            nodeStart[node] = s + excl;
            dinv[node] = rsqrtf((float)cnt[t] + 1.0f);
        }
        cnt[t] = excl;                            // reuse as cursor
    }
    if (b == NBK - 1 && t == 0) nodeStart[N] = E;
    __syncthreads();
    // scatter rows in place (every read already landed in registers)
#pragma unroll
    for (int k = 0; k < KMAX; ++k) {
        if (v[k] >= 0) {
            int rk = atomicAdd(&cnt[v[k] & 511], 1);
            recs[s + rk] = v[k] >> 9;             // store plain row id
        }
    }
}

// ---------- prep: g1 = fp16( dinv * (x @ W1) ) -----------------------------
__global__ void prep_kernel(const float* __restrict__ x, const float* __restrict__ W1,
                            const float* __restrict__ dinv, half4* __restrict__ g1h, int N) {
    int i = blockIdx.x * blockDim.x + threadIdx.x;
    if (i >= N) return;
    float d = dinv[i];
    float acc0 = 0.f, acc1 = 0.f, acc2 = 0.f, acc3 = 0.f;
#pragma unroll
    for (int k = 0; k < 9; ++k) {
        float xv = x[i * 9 + k];
        acc0 += xv * W1[k * 4 + 0];
        acc1 += xv * W1[k * 4 + 1];
        acc2 += xv * W1[k * 4 + 2];
        acc3 += xv * W1[k * 4 + 3];
    }
    half4 h;
    h.x = (_Float16)(d * acc0);
    h.y = (_Float16)(d * acc1);
    h.z = (_Float16)(d * acc2);
    h.w = (_Float16)(d * acc3);
    g1h[i] = h;
}

// ---------- agg layer 1: CSR row-gather, zero atomics, zero LDS ------------
__global__ void agg1_kernel(const int* __restrict__ nodeStart, const int* __restrict__ srows,
                            const float* __restrict__ dinv, const half4* __restrict__ g1h,
                            const float* __restrict__ b1, const float* __restrict__ W2,
                            half2v* __restrict__ g2h, int N) {
    int i = blockIdx.x * blockDim.x + threadIdx.x;
    if (i >= N) return;
    int s = nodeStart[i], e = nodeStart[i + 1];
    float a0 = 0.f, a1 = 0.f, a2 = 0.f, a3 = 0.f;
    int j = s;
    for (; j + 3 < e; j += 4) {
        int r0 = srows[j], r1 = srows[j + 1], r2 = srows[j + 2], r3 = srows[j + 3];
        half4 g0 = g1h[r0];           // 4 independent gathers in flight
        half4 g1 = g1h[r1];
        half4 g2 = g1h[r2];
        half4 g3 = g1h[r3];
        a0 += (float)g0.x + (float)g1.x + (float)g2.x + (float)g3.x;
        a1 += (float)g0.y + (float)g1.y + (float)g2.y + (float)g3.y;
        a2 += (float)g0.z + (float)g1.z + (float)g2.z + (float)g3.z;
        a3 += (float)g0.w + (float)g1.w + (float)g2.w + (float)g3.w;
    }
    for (; j < e; ++j) {
        half4 g = g1h[srows[j]];
        a0 += (float)g.x; a1 += (float)g.y; a2 += (float)g.z; a3 += (float)g.w;
    }
    half4 self = g1h[i];
    float di = dinv[i];
    float t0 = tanhf(di * (a0 + (float)self.x) + b1[0]);
    float t1 = tanhf(di * (a1 + (float)self.y) + b1[1]);
    float t2 = tanhf(di * (a2 + (float)self.z) + b1[2]);
    float t3 = tanhf(di * (a3 + (float)self.w) + b1[3]);
    float o0 = t0 * W2[0] + t1 * W2[2] + t2 * W2[4] + t3 * W2[6];
    float o1 = t0 * W2[1] + t1 * W2[3] + t2 * W2[5] + t3 * W2[7];
    half2v g2o;
    g2o.x = (_Float16)(di * o0);
    g2o.y = (_Float16)(di * o1);
    g2h[i] = g2o;
}

// ---------- agg layer 2: CSR row-gather, zero atomics, zero LDS ------------
__global__ void agg2_kernel(const int* __restrict__ nodeStart, const int* __restrict__ srows,
                            const float* __restrict__ dinv, const half2v* __restrict__ g2h,
                            const float* __restrict__ b2, float* __restrict__ out, int N) {
    int i = blockIdx.x * blockDim.x + threadIdx.x;
    if (i >= N) return;
    int s = nodeStart[i], e = nodeStart[i + 1];
    float a0 = 0.f, a1 = 0.f;
    int j = s;
    for (; j + 3 < e; j += 4) {
        int r0 = srows[j], r1 = srows[j + 1], r2 = srows[j + 2], r3 = srows[j + 3];
        half2v g0 = g2h[r0];
        half2v g1 = g2h[r1];
        half2v g2 = g2h[r2];
        half2v g3 = g2h[r3];
        a0 += (float)g0.x + (float)g1.x + (float)g2.x + (float)g3.x;
        a1 += (float)g0.y + (float)g1.y + (float)g2.y + (float)g3.y;
    }
    for (; j < e; ++j) {
        half2v g = g2h[srows[j]];
        a0 += (float)g.x; a1 += (float)g.y;
    }
    half2v self = g2h[i];
    float di = dinv[i];
    reinterpret_cast<float2*>(out)[i] =
        make_float2(di * (a0 + (float)self.x) + b2[0],
                    di * (a1 + (float)self.y) + b2[1]);
}

extern "C" void kernel_launch(void* const* d_in, const int* in_sizes, int n_in,
                              void* d_out, int out_size, void* d_ws, size_t ws_size,
                              hipStream_t stream) {
    const float* x  = (const float*)d_in[0];
    const int*   ei = (const int*)d_in[1];   // [2, E] int32
    const float* W1 = (const float*)d_in[2];
    const float* b1 = (const float*)d_in[3];
    const float* W2 = (const float*)d_in[4];
    const float* b2 = (const float*)d_in[5];
    float* out = (float*)d_out;

    const int N = NN;
    const int E = in_sizes[1] / 2;           // 16,000,000
    const int* row = ei;
    const int* col = ei + E;

    const int nchunks = (E + CHUNK - 1) / CHUNK;          // 977

    // ws layout (bytes):
    // bucketCount @0 (4K), bucketStart @4K, gcursor @8K,
    // blkCnt(ushort) @16384 (977*2048 = 2,000,896) -> 2,017,280
    // dinv @2,017,280 (2,000,000) -> 4,017,280
    // g1h  @4,017,280 (4,000,000) -> 8,017,280
    // g2h  @8,017,280 (2,000,000) -> 10,017,280
    // nodeStart @10,017,280 ((N+1)*4 = 2,000,004) -> 12,017,284 (pad to 12,017,296)
    // recs @12,017,296 (64,000,000) -> 76,017,296  (< previous 76.6 MB footprint)
    char* ws = (char*)d_ws;
    int*            bucketCount = (int*)ws;
    int*            bucketStart = (int*)(ws + 4096);
    int*            gcursor     = (int*)(ws + 8192);
    unsigned short* blkCnt      = (unsigned short*)(ws + 16384);
    float*          dinv        = (float*)(ws + 2017280ull);
    half4*          g1h         = (half4*)(ws + 4017280ull);
    half2v*         g2h         = (half2v*)(ws + 8017280ull);
    int*            nodeStart   = (int*)(ws + 10017280ull);
    int*            recs        = (int*)(ws + 12017296ull);

    (void)hipMemsetAsync(bucketCount, 0, 4096, stream);

    const int ngrid = (N + 255) / 256;

    hist_kernel<<<nchunks, 256, 0, stream>>>(col, bucketCount, blkCnt, E);
    scan_kernel<<<1, 1024, 0, stream>>>(bucketCount, bucketStart, gcursor);
    part_kernel<<<nchunks, 256, 0, stream>>>(row, col, gcursor, blkCnt, recs, E);
    sort_kernel<<<NBK, 1024, 0, stream>>>(bucketStart, bucketCount, recs, dinv, nodeStart, N, E);
    prep_kernel<<<ngrid, 256, 0, stream>>>(x, W1, dinv, g1h, N);
    agg1_kernel<<<ngrid, 256, 0, stream>>>(nodeStart, recs, dinv, g1h, b1, W2, g2h, N);
    agg2_kernel<<<ngrid, 256, 0, stream>>>(nodeStart, recs, dinv, g2h, b2, out, N);
}

// Round 10
// 699.535 us; speedup vs baseline: 1.4611x; 1.2629x over previous
//
#include <hip/hip_runtime.h>
#include <hip/hip_fp16.h>
#include <math.h>

#define NN 500000
#define BSZ 512                      // nodes per bucket
#define NBK ((NN + BSZ - 1) / BSZ)   // 977 buckets
#define SCH 8192                     // staging chunk (edges) = part granularity
#define KMAX 20                      // max recs/thread in sort (20*1024 >> max bucket ~16.9K)

typedef __attribute__((ext_vector_type(4))) _Float16 half4;
typedef __attribute__((ext_vector_type(2))) _Float16 half2v;
typedef __attribute__((ext_vector_type(4))) int int4v;

// ---------- pass 1: per-chunk bucket histogram; NO global atomics ----------
__global__ void hist_kernel(const int* __restrict__ col, unsigned short* __restrict__ blkCnt,
                            int E, int nch) {
    __shared__ int cnt[4 * 1024];
    int t = threadIdx.x;
    for (int i = t; i < 4096; i += 256) cnt[i] = 0;
    __syncthreads();
    int base = blockIdx.x * (4 * SCH);
    int end = base + 4 * SCH; if (end > E) end = E;
    for (int j = base + t * 4; j < end; j += 1024) {
        int4v c = __builtin_nontemporal_load(reinterpret_cast<const int4v*>(col + j));
        int sub = (j - base) >> 13;                        // chunk within block (0..3)
        atomicAdd(&cnt[sub * 1024 + (c.x >> 9)], 1);
        atomicAdd(&cnt[sub * 1024 + (c.y >> 9)], 1);
        atomicAdd(&cnt[sub * 1024 + (c.z >> 9)], 1);
        atomicAdd(&cnt[sub * 1024 + (c.w >> 9)], 1);
    }
    __syncthreads();
    int chunk0 = blockIdx.x * 4;
#pragma unroll
    for (int s = 0; s < 4; ++s) {
        int c = chunk0 + s;
        if (c >= nch) break;
        for (int b = t; b < 1024; b += 256)
            blkCnt[(size_t)c * 1024 + b] = (unsigned short)cnt[s * 1024 + b];
    }
}

// ---------- pass 2: per-bucket SEQUENTIAL prefix across chunks, in place ---
// Strip k owns the CONTIGUOUS chunk range [k*cps, (k+1)*cps) so that the
// in-place result is a true sequential prefix (part relies on nxt-pre==count).
__global__ void colscan_kernel(unsigned short* __restrict__ blkCnt,
                               int* __restrict__ bucketTotal, int nch) {
    __shared__ int ls[64][5];
    int t = threadIdx.x;
    int cl = t & 3;            // bucket lane (4 buckets/block)
    int bk = t >> 2;           // strip 0..63
    int b = blockIdx.x * 4 + cl;
    int cps = (nch + 63) >> 6; // chunks per strip (contiguous)
    int c0 = bk * cps;
    int c1 = c0 + cps; if (c1 > nch) c1 = nch;
    int run = 0;
    for (int c = c0; c < c1; ++c)
        run += blkCnt[(size_t)c * 1024 + b];
    ls[bk][cl] = run;
    __syncthreads();
    if (t < 4) {               // serial exclusive scan over the 64 strips
        int r = 0;
        for (int k = 0; k < 64; ++k) { int v = ls[k][t]; ls[k][t] = r; r += v; }
        bucketTotal[blockIdx.x * 4 + t] = r;
    }
    __syncthreads();
    int running = ls[bk][cl];
    for (int c = c0; c < c1; ++c) {
        size_t idx = (size_t)c * 1024 + b;
        int v = blkCnt[idx];
        blkCnt[idx] = (unsigned short)running;   // prefix <= bucket total ~17K < 65536
        running += v;
    }
}

// ---------- pass 3: exclusive scan of 1024 bucket totals (1 block) ---------
__global__ void scan_kernel(const int* __restrict__ bucketTotal, int* __restrict__ bucketStart) {
    __shared__ int ls[1024];
    int t = threadIdx.x;
    int v = bucketTotal[t];
    ls[t] = v;
    __syncthreads();
    for (int off = 1; off < 1024; off <<= 1) {
        int u = (t >= off) ? ls[t - off] : 0;
        __syncthreads();
        ls[t] += u;
        __syncthreads();
    }
    bucketStart[t] = ls[t] - v;  // exclusive
}

// ---------- pass 4: partition with LDS staging; NO global atomics ----------
__global__ __launch_bounds__(256) void part_kernel(const int* __restrict__ row,
                                                   const int* __restrict__ col,
                                                   const int* __restrict__ bucketStart,
                                                   const int* __restrict__ bucketTotal,
                                                   const unsigned short* __restrict__ blkPre,
                                                   int* __restrict__ recs, int E, int nch) {
    __shared__ int gbase[1024];
    __shared__ int lexcl[1024];
    __shared__ int cursor[1024];
    __shared__ int ts[256];
    __shared__ int srt[SCH];
    __shared__ unsigned short bkt[SCH];
    int t = threadIdx.x;
    int chunk = blockIdx.x;
    const unsigned short* pre = blkPre + (size_t)chunk * 1024;
    const unsigned short* nxt = blkPre + (size_t)(chunk + 1) * 1024;  // pad row exists
    bool last = (chunk == nch - 1);
    int myc[4];
#pragma unroll
    for (int k = 0; k < 4; ++k) {
        int b = t * 4 + k;
        int p = pre[b];
        int n = last ? bucketTotal[b] : (int)nxt[b];
        myc[k] = n - p;
        gbase[b] = bucketStart[b] + p;
    }
    int tsum = myc[0] + myc[1] + myc[2] + myc[3];
    ts[t] = tsum;
    __syncthreads();
    for (int off = 1; off < 256; off <<= 1) {
        int u = (t >= off) ? ts[t - off] : 0;
        __syncthreads();
        ts[t] += u;
        __syncthreads();
    }
    int r = ts[t] - tsum;      // exclusive over threads
#pragma unroll
    for (int k = 0; k < 4; ++k) {
        int b = t * 4 + k;
        lexcl[b] = r;
        cursor[b] = r;
        r += myc[k];
    }
    __syncthreads();
    // phase 1: rank + stage into LDS (bucket-sorted)
    int base = chunk * SCH;
    int end = base + SCH; if (end > E) end = E;
    for (int j = base + t * 4; j < end; j += 1024) {
        int4v rr = __builtin_nontemporal_load(reinterpret_cast<const int4v*>(row + j));
        int4v cc = __builtin_nontemporal_load(reinterpret_cast<const int4v*>(col + j));
        int b, rk;
        b = cc.x >> 9; rk = atomicAdd(&cursor[b], 1); srt[rk] = (rr.x << 9) | (cc.x & 511); bkt[rk] = (unsigned short)b;
        b = cc.y >> 9; rk = atomicAdd(&cursor[b], 1); srt[rk] = (rr.y << 9) | (cc.y & 511); bkt[rk] = (unsigned short)b;
        b = cc.z >> 9; rk = atomicAdd(&cursor[b], 1); srt[rk] = (rr.z << 9) | (cc.z & 511); bkt[rk] = (unsigned short)b;
        b = cc.w >> 9; rk = atomicAdd(&cursor[b], 1); srt[rk] = (rr.w << 9) | (cc.w & 511); bkt[rk] = (unsigned short)b;
    }
    __syncthreads();
    // phase 2: flush contiguous bucket runs
    int m = end - base;
    for (int p = t; p < m; p += 256) {
        int b = bkt[p];
        recs[gbase[b] + (p - lexcl[b])] = srt[p];
    }
}

// ---------- pass 5: per-bucket counting sort (register-buffered) -----------
__global__ __launch_bounds__(1024) void sort_kernel(const int* __restrict__ bucketStart,
                                                    const int* __restrict__ bucketTotal,
                                                    int* __restrict__ recs,
                                                    float* __restrict__ dinv,
                                                    int* __restrict__ nodeStart, int N, int E) {
    __shared__ int cnt[BSZ];
    __shared__ int sc[BSZ];
    int t = threadIdx.x, b = blockIdx.x;
    int s = bucketStart[b], m = bucketTotal[b];
    int v[KMAX];
#pragma unroll
    for (int k = 0; k < KMAX; ++k) {
        int idx = t + k * 1024;
        v[k] = (idx < m) ? recs[s + idx] : -1;
    }
    if (t < BSZ) cnt[t] = 0;
    __syncthreads();
#pragma unroll
    for (int k = 0; k < KMAX; ++k)
        if (v[k] >= 0) atomicAdd(&cnt[v[k] & 511], 1);
    __syncthreads();
    if (t < BSZ) sc[t] = cnt[t];
    __syncthreads();
    for (int off = 1; off < BSZ; off <<= 1) {
        int u = 0;
        if (t < BSZ && t >= off) u = sc[t - off];
        __syncthreads();
        if (t < BSZ) sc[t] += u;
        __syncthreads();
    }
    if (t < BSZ) {
        int excl = sc[t] - cnt[t];
        int node = b * BSZ + t;
        if (node < N) {
            nodeStart[node] = s + excl;
            dinv[node] = rsqrtf((float)cnt[t] + 1.0f);
        }
        cnt[t] = excl;
    }
    if (b == NBK - 1 && t == 0) nodeStart[N] = E;
    __syncthreads();
#pragma unroll
    for (int k = 0; k < KMAX; ++k) {
        if (v[k] >= 0) {
            int rk = atomicAdd(&cnt[v[k] & 511], 1);
            recs[s + rk] = v[k] >> 9;
        }
    }
}

// ---------- prep: g1 = fp16( dinv * (x @ W1) ) -----------------------------
__global__ void prep_kernel(const float* __restrict__ x, const float* __restrict__ W1,
                            const float* __restrict__ dinv, half4* __restrict__ g1h, int N) {
    int i = blockIdx.x * blockDim.x + threadIdx.x;
    if (i >= N) return;
    float d = dinv[i];
    float acc0 = 0.f, acc1 = 0.f, acc2 = 0.f, acc3 = 0.f;
#pragma unroll
    for (int k = 0; k < 9; ++k) {
        float xv = x[i * 9 + k];
        acc0 += xv * W1[k * 4 + 0];
        acc1 += xv * W1[k * 4 + 1];
        acc2 += xv * W1[k * 4 + 2];
        acc3 += xv * W1[k * 4 + 3];
    }
    half4 h;
    h.x = (_Float16)(d * acc0);
    h.y = (_Float16)(d * acc1);
    h.z = (_Float16)(d * acc2);
    h.w = (_Float16)(d * acc3);
    g1h[i] = h;
}

// ---------- agg layer 1: CSR row-gather, zero atomics ----------------------
__global__ void agg1_kernel(const int* __restrict__ nodeStart, const int* __restrict__ srows,
                            const float* __restrict__ dinv, const half4* __restrict__ g1h,
                            const float* __restrict__ b1, const float* __restrict__ W2,
                            half2v* __restrict__ g2h, int N) {
    int i = blockIdx.x * blockDim.x + threadIdx.x;
    if (i >= N) return;
    int s = nodeStart[i], e = nodeStart[i + 1];
    float a0 = 0.f, a1 = 0.f, a2 = 0.f, a3 = 0.f;
    int j = s;
    for (; j + 3 < e; j += 4) {
        int r0 = srows[j], r1 = srows[j + 1], r2 = srows[j + 2], r3 = srows[j + 3];
        half4 g0 = g1h[r0];
        half4 g1 = g1h[r1];
        half4 g2 = g1h[r2];
        half4 g3 = g1h[r3];
        a0 += (float)g0.x + (float)g1.x + (float)g2.x + (float)g3.x;
        a1 += (float)g0.y + (float)g1.y + (float)g2.y + (float)g3.y;
        a2 += (float)g0.z + (float)g1.z + (float)g2.z + (float)g3.z;
        a3 += (float)g0.w + (float)g1.w + (float)g2.w + (float)g3.w;
    }
    for (; j < e; ++j) {
        half4 g = g1h[srows[j]];
        a0 += (float)g.x; a1 += (float)g.y; a2 += (float)g.z; a3 += (float)g.w;
    }
    half4 self = g1h[i];
    float di = dinv[i];
    float t0 = tanhf(di * (a0 + (float)self.x) + b1[0]);
    float t1 = tanhf(di * (a1 + (float)self.y) + b1[1]);
    float t2 = tanhf(di * (a2 + (float)self.z) + b1[2]);
    float t3 = tanhf(di * (a3 + (float)self.w) + b1[3]);
    float o0 = t0 * W2[0] + t1 * W2[2] + t2 * W2[4] + t3 * W2[6];
    float o1 = t0 * W2[1] + t1 * W2[3] + t2 * W2[5] + t3 * W2[7];
    half2v g2o;
    g2o.x = (_Float16)(di * o0);
    g2o.y = (_Float16)(di * o1);
    g2h[i] = g2o;
}

// ---------- agg layer 2: CSR row-gather, zero atomics ----------------------
__global__ void agg2_kernel(const int* __restrict__ nodeStart, const int* __restrict__ srows,
                            const float* __restrict__ dinv, const half2v* __restrict__ g2h,
                            const float* __restrict__ b2, float* __restrict__ out, int N) {
    int i = blockIdx.x * blockDim.x + threadIdx.x;
    if (i >= N) return;
    int s = nodeStart[i], e = nodeStart[i + 1];
    float a0 = 0.f, a1 = 0.f;
    int j = s;
    for (; j + 3 < e; j += 4) {
        int r0 = srows[j], r1 = srows[j + 1], r2 = srows[j + 2], r3 = srows[j + 3];
        half2v g0 = g2h[r0];
        half2v g1 = g2h[r1];
        half2v g2 = g2h[r2];
        half2v g3 = g2h[r3];
        a0 += (float)g0.x + (float)g1.x + (float)g2.x + (float)g3.x;
        a1 += (float)g0.y + (float)g1.y + (float)g2.y + (float)g3.y;
    }
    for (; j < e; ++j) {
        half2v g = g2h[srows[j]];
        a0 += (float)g.x; a1 += (float)g.y;
    }
    half2v self = g2h[i];
    float di = dinv[i];
    reinterpret_cast<float2*>(out)[i] =
        make_float2(di * (a0 + (float)self.x) + b2[0],
                    di * (a1 + (float)self.y) + b2[1]);
}

extern "C" void kernel_launch(void* const* d_in, const int* in_sizes, int n_in,
                              void* d_out, int out_size, void* d_ws, size_t ws_size,
                              hipStream_t stream) {
    const float* x  = (const float*)d_in[0];
    const int*   ei = (const int*)d_in[1];   // [2, E] int32
    const float* W1 = (const float*)d_in[2];
    const float* b1 = (const float*)d_in[3];
    const float* W2 = (const float*)d_in[4];
    const float* b2 = (const float*)d_in[5];
    float* out = (float*)d_out;

    const int N = NN;
    const int E = in_sizes[1] / 2;           // 16,000,000
    const int* row = ei;
    const int* col = ei + E;

    const int nch = (E + SCH - 1) / SCH;     // 1954 staging chunks

    char* ws = (char*)d_ws;
    size_t off = 0;
    int* bucketTotal = (int*)(ws + off);            off += 4096;
    int* bucketStart = (int*)(ws + off);            off += 4096;
    off = 16384;
    unsigned short* blkCnt = (unsigned short*)(ws + off);
    off += (size_t)(nch + 1) * 1024 * 2;            // ~4.0 MB (pad row for part's nxt)
    off = (off + 15) & ~(size_t)15;
    float*  dinv      = (float*)(ws + off);         off += (size_t)NN * 4;
    off = (off + 15) & ~(size_t)15;
    half4*  g1h       = (half4*)(ws + off);         off += (size_t)NN * 8;
    off = (off + 15) & ~(size_t)15;
    half2v* g2h       = (half2v*)(ws + off);        off += (size_t)NN * 4;
    off = (off + 15) & ~(size_t)15;
    int*    nodeStart = (int*)(ws + off);           off += (size_t)(NN + 1) * 4;
    off = (off + 15) & ~(size_t)15;
    int*    recs      = (int*)(ws + off);

    // zero the blkCnt pad row (speculatively read by part's nxt on the last chunk)
    (void)hipMemsetAsync(blkCnt + (size_t)nch * 1024, 0, 2048, stream);

    const int ngrid = (N + 255) / 256;
    const int hgrid = (nch + 3) / 4;

    hist_kernel   <<<hgrid, 256, 0, stream>>>(col, blkCnt, E, nch);
    colscan_kernel<<<256, 256, 0, stream>>>(blkCnt, bucketTotal, nch);
    scan_kernel   <<<1, 1024, 0, stream>>>(bucketTotal, bucketStart);
    part_kernel   <<<nch, 256, 0, stream>>>(row, col, bucketStart, bucketTotal, blkCnt, recs, E, nch);
    sort_kernel   <<<NBK, 1024, 0, stream>>>(bucketStart, bucketTotal, recs, dinv, nodeStart, N, E);
    prep_kernel   <<<ngrid, 256, 0, stream>>>(x, W1, dinv, g1h, N);
    agg1_kernel   <<<ngrid, 256, 0, stream>>>(nodeStart, recs, dinv, g1h, b1, W2, g2h, N);
    agg2_kernel   <<<ngrid, 256, 0, stream>>>(nodeStart, recs, dinv, g2h, b2, out, N);
}